// Round 3
// baseline (148.325 us; speedup 1.0000x reference)
//
#include <hip/hip_runtime.h>
#include <hip/hip_bf16.h>

// ClassBalancedSupConLoss, B=8192, D=128.
// loss_i = -(BASE/t_i) * [P_i - C_i*(M_i + ln Z_i)] / (C_i + eps)
//   P_i = invt_i * (e_i . S_{c(i)} - ||e_i||^2)   (fp32, closed form)
//   C_i = count_{c(i)} - 1
//   M_i, Z_i: online softmax over bf16-MFMA logits (denominator incl. self).
// k2 trick: B-operand (i side) pre-scaled by invt*log2e -> acc is the
// log2-domain logit directly; update = fmax tree + exp2 only.

#define B_ROWS 8192
#define D_DIM 128
#define BASE_TEMP 0.07f
#define LOG2E 1.4426950408889634f
#define LN2 0.6931471805599453f

typedef __bf16 bf16x8 __attribute__((ext_vector_type(8)));
typedef __bf16 bf16x4 __attribute__((ext_vector_type(4)));
typedef float floatx4 __attribute__((ext_vector_type(4)));

__device__ __forceinline__ float class_invtemp(int lbl) {
    return (lbl == 0) ? 12.5f : ((lbl == 1) ? 20.0f : 10.0f);
}

// ---- K0: cast E -> bf16; per-block class sums + label counts ----
__global__ __launch_bounds__(256) void k0_cast_sums(
        const float* __restrict__ E, const int* __restrict__ labels,
        __bf16* __restrict__ Ebf, float* __restrict__ csum /*[64][3][128]*/,
        float* __restrict__ ccnt /*[64][4]*/) {
    const int blk = blockIdx.x;          // 64 blocks x 128 rows
    const int tid = threadIdx.x;
    const int row0 = blk * 128;

    __shared__ int scnt[3];
    if (tid < 3) scnt[tid] = 0;

    const float4* src = reinterpret_cast<const float4*>(E + (size_t)row0 * D_DIM);
    bf16x4* dst = reinterpret_cast<bf16x4*>(Ebf + (size_t)row0 * D_DIM);
    #pragma unroll
    for (int p = 0; p < 16; ++p) {
        int idx = p * 256 + tid;         // 4096 float4 = 128x128
        float4 v = src[idx];
        bf16x4 o = { (__bf16)v.x, (__bf16)v.y, (__bf16)v.z, (__bf16)v.w };
        dst[idx] = o;
    }

    const int d = tid & 127, half = tid >> 7;
    float s0 = 0.f, s1 = 0.f, s2 = 0.f;
    #pragma unroll 4
    for (int r2 = 0; r2 < 64; ++r2) {
        int r = row0 + half * 64 + r2;
        float v = E[(size_t)r * D_DIM + d];
        int l = labels[r];
        s0 += (l == 0) ? v : 0.f;
        s1 += (l == 1) ? v : 0.f;
        s2 += (l == 2) ? v : 0.f;
    }
    __shared__ float sh[3][128];
    if (half == 1) { sh[0][d] = s0; sh[1][d] = s1; sh[2][d] = s2; }
    __syncthreads();
    if (half == 0) {
        csum[((size_t)blk * 3 + 0) * 128 + d] = s0 + sh[0][d];
        csum[((size_t)blk * 3 + 1) * 128 + d] = s1 + sh[1][d];
        csum[((size_t)blk * 3 + 2) * 128 + d] = s2 + sh[2][d];
    }
    if (tid < 128) atomicAdd(&scnt[labels[row0 + tid]], 1);
    __syncthreads();
    if (tid < 3) ccnt[blk * 4 + tid] = (float)scnt[tid];
}

// ---- K0b: reduce class sums + counts ----
__global__ __launch_bounds__(256) void k0b_reduce(
        const float* __restrict__ csum, const float* __restrict__ ccnt,
        float* __restrict__ S /*[3][128]*/, float* __restrict__ counts /*[3]*/) {
    const int tid = threadIdx.x;
    if (tid < 128) {
        #pragma unroll
        for (int c = 0; c < 3; ++c) {
            float a = 0.f;
            #pragma unroll 8
            for (int blk = 0; blk < 64; ++blk)
                a += csum[((size_t)blk * 3 + c) * 128 + tid];
            S[c * 128 + tid] = a;
        }
    } else if (tid < 131) {
        int c = tid - 128;
        float a = 0.f;
        #pragma unroll 8
        for (int blk = 0; blk < 64; ++blk) a += ccnt[blk * 4 + c];
        counts[c] = a;
    }
}

// ---- K2: 16x16x32 bf16 MFMA -> per-(row,split) online (m, Z), log2 domain ----
// grid (128, nsplit); block 256 = 4 waves; wave owns 16 i-cols, steps 16 j.
__global__ __launch_bounds__(256) void k2_stats(
        const __bf16* __restrict__ Ebf, const int* __restrict__ labels,
        float2* __restrict__ part, int nsplit, int jrange) {
    const int lane = threadIdx.x & 63;
    const int wave = threadIdx.x >> 6;
    const int split = blockIdx.y;
    const int j0 = split * jrange;
    const int il = lane & 15;          // i-col within wave tile
    const int kg = lane >> 4;          // k-group 0..3
    const int icol = blockIdx.x * 64 + wave * 16 + il;

    const float bscale = class_invtemp(labels[icol]) * LOG2E;

    // B frag (i side), pre-scaled: k = c*32 + kg*8 + e
    bf16x8 Bf[4];
    {
        const __bf16* bp = Ebf + (size_t)icol * D_DIM + kg * 8;
        #pragma unroll
        for (int c = 0; c < 4; ++c) {
            bf16x8 raw = *reinterpret_cast<const bf16x8*>(bp + c * 32);
            bf16x8 sc;
            #pragma unroll
            for (int e = 0; e < 8; ++e) sc[e] = (__bf16)((float)raw[e] * bscale);
            Bf[c] = sc;
        }
    }

    // A frag (j side): row = j0 + step*16 + il, k = c*32 + kg*8 + e
    const __bf16* aptr = Ebf + ((size_t)j0 + il) * D_DIM + kg * 8;
    const size_t STEP = (size_t)16 * D_DIM;

    bf16x8 A0[4], A1[4];
    #pragma unroll
    for (int c = 0; c < 4; ++c)
        A0[c] = *reinterpret_cast<const bf16x8*>(aptr + c * 32);

    float m = -3.0e38f, Z = 0.f;
    const int nsteps = jrange >> 4;

#define MFMA_STEP(Abuf)                                                        \
    {                                                                          \
        floatx4 acc = {0.f, 0.f, 0.f, 0.f};                                    \
        acc = __builtin_amdgcn_mfma_f32_16x16x32_bf16(Abuf[0], Bf[0], acc, 0, 0, 0); \
        acc = __builtin_amdgcn_mfma_f32_16x16x32_bf16(Abuf[1], Bf[1], acc, 0, 0, 0); \
        acc = __builtin_amdgcn_mfma_f32_16x16x32_bf16(Abuf[2], Bf[2], acc, 0, 0, 0); \
        acc = __builtin_amdgcn_mfma_f32_16x16x32_bf16(Abuf[3], Bf[3], acc, 0, 0, 0); \
        float v01 = fmaxf(acc[0], acc[1]);                                     \
        float v23 = fmaxf(acc[2], acc[3]);                                     \
        float nm = fmaxf(m, fmaxf(v01, v23));                                  \
        float z = __builtin_amdgcn_exp2f(acc[0] - nm)                          \
                + __builtin_amdgcn_exp2f(acc[1] - nm)                          \
                + __builtin_amdgcn_exp2f(acc[2] - nm)                          \
                + __builtin_amdgcn_exp2f(acc[3] - nm);                         \
        Z = fmaf(Z, __builtin_amdgcn_exp2f(m - nm), z);                        \
        m = nm;                                                                \
    }

    for (int s = 0; s < nsteps; s += 2) {
        {   // consume A0, prefetch s+1 -> A1
            const __bf16* ap = aptr + (size_t)(s + 1) * STEP;
            #pragma unroll
            for (int c = 0; c < 4; ++c)
                A1[c] = *reinterpret_cast<const bf16x8*>(ap + c * 32);
            MFMA_STEP(A0)
        }
        {   // consume A1, prefetch s+2 -> A0
            if (s + 2 < nsteps) {
                const __bf16* ap = aptr + (size_t)(s + 2) * STEP;
                #pragma unroll
                for (int c = 0; c < 4; ++c)
                    A0[c] = *reinterpret_cast<const bf16x8*>(ap + c * 32);
            }
            MFMA_STEP(A1)
        }
    }
#undef MFMA_STEP

    // merge the 4 k-groups (same i-col in lanes il, il+16, il+32, il+48)
    #pragma unroll
    for (int off = 16; off <= 32; off <<= 1) {
        float om = __shfl_xor(m, off);
        float oZ = __shfl_xor(Z, off);
        float nm = fmaxf(m, om);
        Z = Z * __builtin_amdgcn_exp2f(m - nm) + oZ * __builtin_amdgcn_exp2f(om - nm);
        m = nm;
    }
    if (kg == 0)
        part[(size_t)icol * nsplit + split] = make_float2(m, Z);
}

// ---- K3: per-row loss + per-block partial sum ----
__global__ __launch_bounds__(256) void k3_rowloss(
        const float* __restrict__ E, const int* __restrict__ labels,
        const float* __restrict__ S, const float* __restrict__ counts,
        const float2* __restrict__ part, int nsplit,
        float* __restrict__ bpart /*[32][2]*/) {
    __shared__ float sS[3][128];
    const int tid = threadIdx.x;
    if (tid < 128) {
        sS[0][tid] = S[tid];
        sS[1][tid] = S[128 + tid];
        sS[2][tid] = S[256 + tid];
    }
    __syncthreads();

    const int i = blockIdx.x * 256 + tid;
    const int lab = labels[i];
    const float invt = class_invtemp(lab);

    const float4* er = reinterpret_cast<const float4*>(E + (size_t)i * D_DIM);
    const float4* sr = reinterpret_cast<const float4*>(&sS[lab][0]);
    float dotS = 0.f, nrm = 0.f;
    #pragma unroll
    for (int k4 = 0; k4 < 32; ++k4) {
        float4 v = er[k4];
        float4 s = sr[k4];
        dotS += v.x * s.x + v.y * s.y + v.z * s.z + v.w * s.w;
        nrm  += v.x * v.x + v.y * v.y + v.z * v.z + v.w * v.w;
    }

    float m = -3.0e38f, Z = 0.f;
    for (int sp = 0; sp < nsplit; ++sp) {
        float2 p = part[(size_t)i * nsplit + sp];
        float nm = fmaxf(m, p.x);
        Z = Z * __builtin_amdgcn_exp2f(m - nm) + p.y * __builtin_amdgcn_exp2f(p.x - nm);
        m = nm;
    }

    const float C = counts[lab] - 1.0f;
    const float M_nat = m * LN2;                                  // m is log2-domain
    const float lnZ = LN2 * __builtin_amdgcn_logf(Z + 1e-8f);     // ln(sumexp + eps)
    const float P_nat = invt * (dotS - nrm);
    float loss = -(BASE_TEMP * invt) * (P_nat - C * (M_nat + lnZ)) / (C + 1e-8f);
    float valid = (C > 0.f) ? 1.f : 0.f;
    loss = (C > 0.f) ? loss : 0.f;

    #pragma unroll
    for (int off = 32; off; off >>= 1) {
        loss += __shfl_down(loss, off);
        valid += __shfl_down(valid, off);
    }
    __shared__ float rs[4][2];
    const int w = tid >> 6;
    if ((tid & 63) == 0) { rs[w][0] = loss; rs[w][1] = valid; }
    __syncthreads();
    if (tid == 0) {
        bpart[blockIdx.x * 2 + 0] = rs[0][0] + rs[1][0] + rs[2][0] + rs[3][0];
        bpart[blockIdx.x * 2 + 1] = rs[0][1] + rs[1][1] + rs[2][1] + rs[3][1];
    }
}

// ---- K4: final scalar ----
__global__ void k4_final(const float* __restrict__ bpart, float* __restrict__ out) {
    const int lane = threadIdx.x;
    float T = 0.f, N = 0.f;
    if (lane < 32) { T = bpart[lane * 2]; N = bpart[lane * 2 + 1]; }
    #pragma unroll
    for (int off = 32; off; off >>= 1) {
        T += __shfl_down(T, off);
        N += __shfl_down(N, off);
    }
    if (lane == 0) out[0] = (N > 0.f) ? T / fmaxf(N, 1.f) : 0.f;
}

extern "C" void kernel_launch(void* const* d_in, const int* in_sizes, int n_in,
                              void* d_out, int out_size, void* d_ws, size_t ws_size,
                              hipStream_t stream) {
    const float* E = (const float*)d_in[0];
    const int* labels = (const int*)d_in[1];
    float* out = (float*)d_out;
    char* ws = (char*)d_ws;

    // workspace layout
    const size_t OFF_EBF = 0;                       // 2 MB bf16 E
    const size_t OFF_CSUM = (size_t)2 << 20;        // 64*3*128*4 = 96 KB
    const size_t OFF_CCNT = OFF_CSUM + 98304;       // 64*4*4 = 1 KB
    const size_t OFF_S = OFF_CCNT + 1024;           // 1536 B
    const size_t OFF_CNT = OFF_S + 1536;            // 12 B (+pad)
    const size_t OFF_BPART = OFF_CNT + 64;          // 256 B
    const size_t OFF_PART = OFF_CSUM + (128 << 10); // float2 per (row, split)

    int nsplit = 4;
    if (ws_size >= OFF_PART + (size_t)B_ROWS * 16 * 8) nsplit = 16;
    else if (ws_size >= OFF_PART + (size_t)B_ROWS * 8 * 8) nsplit = 8;
    const int jrange = B_ROWS / nsplit;

    __bf16* Ebf = (__bf16*)(ws + OFF_EBF);
    float* csum = (float*)(ws + OFF_CSUM);
    float* ccnt = (float*)(ws + OFF_CCNT);
    float* S = (float*)(ws + OFF_S);
    float* counts = (float*)(ws + OFF_CNT);
    float* bpart = (float*)(ws + OFF_BPART);
    float2* part = (float2*)(ws + OFF_PART);

    k0_cast_sums<<<64, 256, 0, stream>>>(E, labels, Ebf, csum, ccnt);
    k0b_reduce<<<1, 256, 0, stream>>>(csum, ccnt, S, counts);
    k2_stats<<<dim3(128, nsplit), 256, 0, stream>>>(Ebf, labels, part, nsplit, jrange);
    k3_rowloss<<<32, 256, 0, stream>>>(E, labels, S, counts, part, nsplit, bpart);
    k4_final<<<1, 64, 0, stream>>>(bpart, out);
}

// Round 4
// 54.419 us; speedup vs baseline: 2.7256x; 2.7256x over previous
//
#include <hip/hip_runtime.h>
#include <hip/hip_bf16.h>

// ClassBalancedSupConLoss, B=8192, D=128.
// loss_i = -(BASE/t_i) * [P_i - C_i*(M_i + ln Z_i)] / (C_i + eps)
//   P_i = invt_i * (e_i . S_{c(i)} - ||e_i||^2)   (fp32, closed form)
//   C_i = count_{c(i)} - 1
//   M_i, Z_i: online softmax over bf16-MFMA logits (denominator incl. self).
// k2: 32x32x16 bf16 MFMA, swapped operands (A=j rows, B=i cols pre-scaled by
// invt*log2e) -> acc IS the log2-domain logit; lane owns one i-col, 16 j's.
// Ebf stored in MFMA-fragment-tiled order: element (r,k) -> tile r>>5,
// chunk k>>4, lane (r&31)+((k>>3)&1)*32, e k&7 -> all k2 loads lane-contiguous.
// k/j permutations are dot/softmax-invariant; only the i mapping is critical.

#define B_ROWS 8192
#define D_DIM 128
#define BASE_TEMP 0.07f
#define LOG2E 1.4426950408889634f
#define LN2 0.6931471805599453f

typedef __bf16 bf16x8 __attribute__((ext_vector_type(8)));
typedef __bf16 bf16x4 __attribute__((ext_vector_type(4)));
typedef float floatx16 __attribute__((ext_vector_type(16)));

__device__ __forceinline__ float class_invtemp(int lbl) {
    return (lbl == 0) ? 12.5f : ((lbl == 1) ? 20.0f : 10.0f);
}

// ---- K0: cast E -> bf16 tiled fragment layout; class sums + counts ----
__global__ __launch_bounds__(256) void k0_cast_sums(
        const float* __restrict__ E, const int* __restrict__ labels,
        __bf16* __restrict__ Ebf, float* __restrict__ csum /*[64][3][128]*/,
        float* __restrict__ ccnt /*[64][4]*/) {
    const int blk = blockIdx.x;          // 64 blocks x 128 rows
    const int tid = threadIdx.x;
    const int row0 = blk * 128;

    __shared__ int scnt[3];
    if (tid < 3) scnt[tid] = 0;

    const float4* src = reinterpret_cast<const float4*>(E + (size_t)row0 * D_DIM);
    #pragma unroll
    for (int p = 0; p < 16; ++p) {
        int idx = p * 256 + tid;         // 4096 float4 = 128 rows x 32 k4
        float4 v = src[idx];
        int r = idx >> 5, k4 = idx & 31;
        int R = row0 + r;
        int T = R >> 5;
        int l = (R & 31) + ((k4 >> 1) & 1) * 32;
        int c = k4 >> 2;
        size_t dst = (size_t)T * 4096 + c * 512 + l * 8 + (k4 & 1) * 4;
        bf16x4 o = { (__bf16)v.x, (__bf16)v.y, (__bf16)v.z, (__bf16)v.w };
        *reinterpret_cast<bf16x4*>(Ebf + dst) = o;
    }

    const int d = tid & 127, half = tid >> 7;
    float s0 = 0.f, s1 = 0.f, s2 = 0.f;
    #pragma unroll 4
    for (int r2 = 0; r2 < 64; ++r2) {
        int r = row0 + half * 64 + r2;
        float v = E[(size_t)r * D_DIM + d];
        int l = labels[r];
        s0 += (l == 0) ? v : 0.f;
        s1 += (l == 1) ? v : 0.f;
        s2 += (l == 2) ? v : 0.f;
    }
    __shared__ float sh[3][128];
    if (half == 1) { sh[0][d] = s0; sh[1][d] = s1; sh[2][d] = s2; }
    __syncthreads();
    if (half == 0) {
        csum[((size_t)blk * 3 + 0) * 128 + d] = s0 + sh[0][d];
        csum[((size_t)blk * 3 + 1) * 128 + d] = s1 + sh[1][d];
        csum[((size_t)blk * 3 + 2) * 128 + d] = s2 + sh[2][d];
    }
    if (tid < 128) atomicAdd(&scnt[labels[row0 + tid]], 1);
    __syncthreads();
    if (tid < 3) ccnt[blk * 4 + tid] = (float)scnt[tid];
}

// ---- K0b: reduce class sums + counts ----
__global__ __launch_bounds__(256) void k0b_reduce(
        const float* __restrict__ csum, const float* __restrict__ ccnt,
        float* __restrict__ S /*[3][128]*/, float* __restrict__ counts /*[3]*/) {
    const int tid = threadIdx.x;
    if (tid < 128) {
        #pragma unroll
        for (int c = 0; c < 3; ++c) {
            float a = 0.f;
            #pragma unroll 8
            for (int blk = 0; blk < 64; ++blk)
                a += csum[((size_t)blk * 3 + c) * 128 + tid];
            S[c * 128 + tid] = a;
        }
    } else if (tid < 131) {
        int c = tid - 128;
        float a = 0.f;
        #pragma unroll 8
        for (int blk = 0; blk < 64; ++blk) a += ccnt[blk * 4 + c];
        counts[c] = a;
    }
}

// ---- K2: tiled-layout 32x32x16 MFMA -> per-(row,split) online (m,Z) ----
// grid (64, nsplit); block 256 = 4 waves; wave owns 32 i-cols.
__global__ __launch_bounds__(256, 3) void k2_stats(
        const __bf16* __restrict__ Ebf, const int* __restrict__ labels,
        float2* __restrict__ part, int nsplit, int jrange) {
    const int lane = threadIdx.x & 63;
    const int wave = threadIdx.x >> 6;
    const int split = blockIdx.y;
    const int j0 = split * jrange;
    const int col = lane & 31;
    const int icol = blockIdx.x * 128 + wave * 32 + col;

    const float bscale = class_invtemp(labels[icol]) * LOG2E;

    // B frag (i side), pre-scaled, from tiled layout
    const int iT = blockIdx.x * 4 + wave;
    const __bf16* bbase = Ebf + (size_t)iT * 4096 + lane * 8;
    bf16x8 Bf[8];
    #pragma unroll
    for (int c = 0; c < 8; ++c) {
        bf16x8 raw = *reinterpret_cast<const bf16x8*>(bbase + c * 512);
        bf16x8 sc;
        #pragma unroll
        for (int e = 0; e < 8; ++e) sc[e] = (__bf16)((float)raw[e] * bscale);
        Bf[c] = sc;
    }

    // A frags (j side): tile s covers j rows [j0 + s*32, +32)
    const __bf16* abase = Ebf + ((size_t)(j0 >> 5)) * 4096 + lane * 8;
    bf16x8 A0[8], A1[8];
    #pragma unroll
    for (int c = 0; c < 8; ++c)
        A0[c] = *reinterpret_cast<const bf16x8*>(abase + c * 512);

    float m[2] = { -3.0e38f, -3.0e38f };
    float Z[2] = { 0.f, 0.f };
    const int nsteps = jrange >> 5;

    auto k2_step = [&](const bf16x8* Ab, int ch) {
        floatx16 a0, a1;
        #pragma unroll
        for (int r = 0; r < 16; ++r) { a0[r] = 0.f; a1[r] = 0.f; }
        a0 = __builtin_amdgcn_mfma_f32_32x32x16_bf16(Ab[0], Bf[0], a0, 0, 0, 0);
        a1 = __builtin_amdgcn_mfma_f32_32x32x16_bf16(Ab[4], Bf[4], a1, 0, 0, 0);
        a0 = __builtin_amdgcn_mfma_f32_32x32x16_bf16(Ab[1], Bf[1], a0, 0, 0, 0);
        a1 = __builtin_amdgcn_mfma_f32_32x32x16_bf16(Ab[5], Bf[5], a1, 0, 0, 0);
        a0 = __builtin_amdgcn_mfma_f32_32x32x16_bf16(Ab[2], Bf[2], a0, 0, 0, 0);
        a1 = __builtin_amdgcn_mfma_f32_32x32x16_bf16(Ab[6], Bf[6], a1, 0, 0, 0);
        a0 = __builtin_amdgcn_mfma_f32_32x32x16_bf16(Ab[3], Bf[3], a0, 0, 0, 0);
        a1 = __builtin_amdgcn_mfma_f32_32x32x16_bf16(Ab[7], Bf[7], a1, 0, 0, 0);
        float v[16];
        #pragma unroll
        for (int r = 0; r < 16; ++r) v[r] = a0[r] + a1[r];
        float x0 = fmaxf(v[0], v[1]),   x1 = fmaxf(v[2], v[3]);
        float x2 = fmaxf(v[4], v[5]),   x3 = fmaxf(v[6], v[7]);
        float x4 = fmaxf(v[8], v[9]),   x5 = fmaxf(v[10], v[11]);
        float x6 = fmaxf(v[12], v[13]), x7 = fmaxf(v[14], v[15]);
        float mx = fmaxf(fmaxf(fmaxf(x0, x1), fmaxf(x2, x3)),
                         fmaxf(fmaxf(x4, x5), fmaxf(x6, x7)));
        float nm = fmaxf(m[ch], mx);
        float z[16];
        #pragma unroll
        for (int r = 0; r < 16; ++r) z[r] = __builtin_amdgcn_exp2f(v[r] - nm);
        float t0 = (z[0] + z[1]) + (z[2] + z[3]);
        float t1 = (z[4] + z[5]) + (z[6] + z[7]);
        float t2 = (z[8] + z[9]) + (z[10] + z[11]);
        float t3 = (z[12] + z[13]) + (z[14] + z[15]);
        Z[ch] = fmaf(Z[ch], __builtin_amdgcn_exp2f(m[ch] - nm), (t0 + t1) + (t2 + t3));
        m[ch] = nm;
    };

    for (int s = 0; s < nsteps; s += 2) {
        {   // consume A0 (step s), prefetch s+1 -> A1
            const __bf16* ap = abase + (size_t)(s + 1) * 4096;
            #pragma unroll
            for (int c = 0; c < 8; ++c)
                A1[c] = *reinterpret_cast<const bf16x8*>(ap + c * 512);
            k2_step(A0, 0);
        }
        {   // consume A1 (step s+1), prefetch s+2 -> A0
            if (s + 2 < nsteps) {
                const __bf16* ap = abase + (size_t)(s + 2) * 4096;
                #pragma unroll
                for (int c = 0; c < 8; ++c)
                    A0[c] = *reinterpret_cast<const bf16x8*>(ap + c * 512);
            }
            k2_step(A1, 1);
        }
    }

    // merge the two chains
    float nm = fmaxf(m[0], m[1]);
    float Zm = Z[0] * __builtin_amdgcn_exp2f(m[0] - nm)
             + Z[1] * __builtin_amdgcn_exp2f(m[1] - nm);

    // lanes l and l+32 hold the same i-col: merge
    float om = __shfl_xor(nm, 32), oZ = __shfl_xor(Zm, 32);
    float fm = fmaxf(nm, om);
    float fZ = Zm * __builtin_amdgcn_exp2f(nm - fm)
             + oZ * __builtin_amdgcn_exp2f(om - fm);
    if (lane < 32)
        part[(size_t)icol * nsplit + split] = make_float2(fm, fZ);
}

// ---- K3: per-row loss + per-block partial sum ----
__global__ __launch_bounds__(256) void k3_rowloss(
        const float* __restrict__ E, const int* __restrict__ labels,
        const float* __restrict__ S, const float* __restrict__ counts,
        const float2* __restrict__ part, int nsplit,
        float* __restrict__ bpart /*[32][2]*/) {
    __shared__ float sS[3][128];
    const int tid = threadIdx.x;
    if (tid < 128) {
        sS[0][tid] = S[tid];
        sS[1][tid] = S[128 + tid];
        sS[2][tid] = S[256 + tid];
    }
    __syncthreads();

    const int i = blockIdx.x * 256 + tid;
    const int lab = labels[i];
    const float invt = class_invtemp(lab);

    const float4* er = reinterpret_cast<const float4*>(E + (size_t)i * D_DIM);
    const float4* sr = reinterpret_cast<const float4*>(&sS[lab][0]);
    float dotS = 0.f, nrm = 0.f;
    #pragma unroll
    for (int k4 = 0; k4 < 32; ++k4) {
        float4 v = er[k4];
        float4 s = sr[k4];
        dotS += v.x * s.x + v.y * s.y + v.z * s.z + v.w * s.w;
        nrm  += v.x * v.x + v.y * v.y + v.z * v.z + v.w * v.w;
    }

    float m = -3.0e38f, Z = 0.f;
    for (int sp = 0; sp < nsplit; ++sp) {
        float2 p = part[(size_t)i * nsplit + sp];
        float nm = fmaxf(m, p.x);
        Z = Z * __builtin_amdgcn_exp2f(m - nm) + p.y * __builtin_amdgcn_exp2f(p.x - nm);
        m = nm;
    }

    const float C = counts[lab] - 1.0f;
    const float M_nat = m * LN2;                                  // m is log2-domain
    const float lnZ = LN2 * __builtin_amdgcn_logf(Z + 1e-8f);     // ln(sumexp + eps)
    const float P_nat = invt * (dotS - nrm);
    float loss = -(BASE_TEMP * invt) * (P_nat - C * (M_nat + lnZ)) / (C + 1e-8f);
    float valid = (C > 0.f) ? 1.f : 0.f;
    loss = (C > 0.f) ? loss : 0.f;

    #pragma unroll
    for (int off = 32; off; off >>= 1) {
        loss += __shfl_down(loss, off);
        valid += __shfl_down(valid, off);
    }
    __shared__ float rs[4][2];
    const int w = tid >> 6;
    if ((tid & 63) == 0) { rs[w][0] = loss; rs[w][1] = valid; }
    __syncthreads();
    if (tid == 0) {
        bpart[blockIdx.x * 2 + 0] = rs[0][0] + rs[1][0] + rs[2][0] + rs[3][0];
        bpart[blockIdx.x * 2 + 1] = rs[0][1] + rs[1][1] + rs[2][1] + rs[3][1];
    }
}

// ---- K4: final scalar ----
__global__ void k4_final(const float* __restrict__ bpart, float* __restrict__ out) {
    const int lane = threadIdx.x;
    float T = 0.f, N = 0.f;
    if (lane < 32) { T = bpart[lane * 2]; N = bpart[lane * 2 + 1]; }
    #pragma unroll
    for (int off = 32; off; off >>= 1) {
        T += __shfl_down(T, off);
        N += __shfl_down(N, off);
    }
    if (lane == 0) out[0] = (N > 0.f) ? T / fmaxf(N, 1.f) : 0.f;
}

extern "C" void kernel_launch(void* const* d_in, const int* in_sizes, int n_in,
                              void* d_out, int out_size, void* d_ws, size_t ws_size,
                              hipStream_t stream) {
    const float* E = (const float*)d_in[0];
    const int* labels = (const int*)d_in[1];
    float* out = (float*)d_out;
    char* ws = (char*)d_ws;

    // workspace layout
    const size_t OFF_EBF = 0;                       // 2 MB bf16 E (tiled)
    const size_t OFF_CSUM = (size_t)2 << 20;        // 64*3*128*4 = 96 KB
    const size_t OFF_CCNT = OFF_CSUM + 98304;       // 64*4*4 = 1 KB
    const size_t OFF_S = OFF_CCNT + 1024;           // 1536 B
    const size_t OFF_CNT = OFF_S + 1536;            // 12 B (+pad)
    const size_t OFF_BPART = OFF_CNT + 64;          // 256 B
    const size_t OFF_PART = OFF_CSUM + (128 << 10); // float2 per (row, split)

    int nsplit = 4;
    if (ws_size >= OFF_PART + (size_t)B_ROWS * 16 * 8) nsplit = 16;
    else if (ws_size >= OFF_PART + (size_t)B_ROWS * 8 * 8) nsplit = 8;
    const int jrange = B_ROWS / nsplit;

    __bf16* Ebf = (__bf16*)(ws + OFF_EBF);
    float* csum = (float*)(ws + OFF_CSUM);
    float* ccnt = (float*)(ws + OFF_CCNT);
    float* S = (float*)(ws + OFF_S);
    float* counts = (float*)(ws + OFF_CNT);
    float* bpart = (float*)(ws + OFF_BPART);
    float2* part = (float2*)(ws + OFF_PART);

    k0_cast_sums<<<64, 256, 0, stream>>>(E, labels, Ebf, csum, ccnt);
    k0b_reduce<<<1, 256, 0, stream>>>(csum, ccnt, S, counts);
    k2_stats<<<dim3(64, nsplit), 256, 0, stream>>>(Ebf, labels, part, nsplit, jrange);
    k3_rowloss<<<32, 256, 0, stream>>>(E, labels, S, counts, part, nsplit, bpart);
    k4_final<<<1, 64, 0, stream>>>(bpart, out);
}

// Round 5
// 50.818 us; speedup vs baseline: 2.9187x; 1.0709x over previous
//
#include <hip/hip_runtime.h>
#include <hip/hip_bf16.h>

// ClassBalancedSupConLoss, B=8192, D=128.
// loss_i = -(BASE/t_i)*[P_i - C_i*lse_i]/(C_i+eps)
//   P_i   = invt_i*(e_i.S_{c(i)} - ||e_i||^2)      (fp32 closed form)
//   C_i   = count_{c(i)} - 1
//   lse_i = log(sum_j exp(logit_ij))  via FIXED-reference softmax:
//           Z_i = sum_j exp2(v_ij - m_i), m_i = invt_i*log2e*||e_i||^2
//           (exact for any fixed m_i; self-logit dominates -> no overflow)
// k2: 32x32x16 bf16 MFMA, swapped operands (A=j rows, B=i cols pre-scaled by
// invt*log2e); one accumulator chain initialized to -m so exp2 args come
// straight from the matrix pipe. Ebf stored in MFMA-fragment-tiled order
// (validated r4): (r,k) -> tile r>>5, chunk k>>4, lane (r&31)+((k>>3)&1)*32.
// All cross-block reductions use fixed-point int64 atomics (deterministic).

#define B_ROWS 8192
#define D_DIM 128
#define BASE_TEMP 0.07f
#define LOG2E 1.4426950408889634f
#define LN2 0.6931471805599453f
#define FIX_SCALE 1048576.0f   // 2^20

typedef __bf16 bf16x8 __attribute__((ext_vector_type(8)));
typedef __bf16 bf16x4 __attribute__((ext_vector_type(4)));
typedef float floatx16 __attribute__((ext_vector_type(16)));

__device__ __forceinline__ float class_invtemp(int lbl) {
    return (lbl == 0) ? 12.5f : ((lbl == 1) ? 20.0f : 10.0f);
}

__device__ __forceinline__ unsigned long long fix64(float v) {
    return (unsigned long long)(long long)llrintf(v * FIX_SCALE);
}

// ---- K0: cast->tiled bf16, row norms, class sums/counts (fixed-point) ----
__global__ __launch_bounds__(256) void k0_prep(
        const float* __restrict__ E, const int* __restrict__ labels,
        __bf16* __restrict__ Ebf, float* __restrict__ nrm,
        unsigned long long* __restrict__ Sfix /*[3*128]*/,
        unsigned long long* __restrict__ cntfix /*[3]*/) {
    const int blk = blockIdx.x;          // 256 blocks x 32 rows
    const int tid = threadIdx.x;
    const int row0 = blk * 32;

    __shared__ float sh[3][128];
    __shared__ int scnt[3];
    if (tid < 3) scnt[tid] = 0;

    // cast to tiled fragment layout (mapping validated in r4)
    const float4* src = reinterpret_cast<const float4*>(E + (size_t)row0 * D_DIM);
    #pragma unroll
    for (int p = 0; p < 4; ++p) {
        int idx = p * 256 + tid;         // 1024 float4 = 32 rows x 32 k4
        float4 v = src[idx];
        int r = idx >> 5, k4 = idx & 31;
        int R = row0 + r;
        int T = R >> 5;
        int l = (R & 31) + ((k4 >> 1) & 1) * 32;
        int c = k4 >> 2;
        size_t dst = (size_t)T * 4096 + c * 512 + l * 8 + (k4 & 1) * 4;
        bf16x4 o = { (__bf16)v.x, (__bf16)v.y, (__bf16)v.z, (__bf16)v.w };
        *reinterpret_cast<bf16x4*>(Ebf + dst) = o;
    }

    // row norms: 8 threads per row
    {
        int r = tid >> 3, g = tid & 7;
        const float4* er = reinterpret_cast<const float4*>(
            E + (size_t)(row0 + r) * D_DIM + g * 16);
        float s = 0.f;
        #pragma unroll
        for (int q = 0; q < 4; ++q) {
            float4 v = er[q];
            s += v.x * v.x + v.y * v.y + v.z * v.z + v.w * v.w;
        }
        s += __shfl_xor(s, 1); s += __shfl_xor(s, 2); s += __shfl_xor(s, 4);
        if (g == 0) nrm[row0 + r] = s;
    }

    // class sums: thread d over 16 rows (two halves)
    const int d = tid & 127, half = tid >> 7;
    float s0 = 0.f, s1 = 0.f, s2 = 0.f;
    #pragma unroll 4
    for (int r2 = 0; r2 < 16; ++r2) {
        int r = row0 + half * 16 + r2;
        float v = E[(size_t)r * D_DIM + d];
        int l = labels[r];
        s0 += (l == 0) ? v : 0.f;
        s1 += (l == 1) ? v : 0.f;
        s2 += (l == 2) ? v : 0.f;
    }
    if (half == 1) { sh[0][d] = s0; sh[1][d] = s1; sh[2][d] = s2; }
    __syncthreads();
    if (half == 0) {
        atomicAdd(&Sfix[d],       fix64(s0 + sh[0][d]));
        atomicAdd(&Sfix[128 + d], fix64(s1 + sh[1][d]));
        atomicAdd(&Sfix[256 + d], fix64(s2 + sh[2][d]));
    }
    if (tid < 32) atomicAdd(&scnt[labels[row0 + tid]], 1);
    __syncthreads();
    if (tid < 3) atomicAdd(&cntfix[tid], (unsigned long long)scnt[tid]);
}

// ---- K2: fixed-m softmax denominators; part[split][i] = Z partial ----
__global__ __launch_bounds__(256, 3) void k2_stats(
        const __bf16* __restrict__ Ebf, const int* __restrict__ labels,
        const float* __restrict__ nrm, float* __restrict__ part,
        int nsplit, int jrange) {
    const int lane = threadIdx.x & 63;
    const int wave = threadIdx.x >> 6;
    const int split = blockIdx.y;
    const int j0 = split * jrange;
    const int col = lane & 31;
    const int icol = blockIdx.x * 128 + wave * 32 + col;

    const float bscale = class_invtemp(labels[icol]) * LOG2E;
    const float m = bscale * nrm[icol];   // log2-domain self logit (fp32-exact ref)

    // B frag (i side), pre-scaled, tiled layout
    const int iT = blockIdx.x * 4 + wave;
    const __bf16* bbase = Ebf + (size_t)iT * 4096 + lane * 8;
    bf16x8 Bf[8];
    #pragma unroll
    for (int c = 0; c < 8; ++c) {
        bf16x8 raw = *reinterpret_cast<const bf16x8*>(bbase + c * 512);
        bf16x8 sc;
        #pragma unroll
        for (int e = 0; e < 8; ++e) sc[e] = (__bf16)((float)raw[e] * bscale);
        Bf[c] = sc;
    }

    const __bf16* abase = Ebf + ((size_t)(j0 >> 5)) * 4096 + lane * 8;
    bf16x8 A0[8], A1[8];
    #pragma unroll
    for (int c = 0; c < 8; ++c)
        A0[c] = *reinterpret_cast<const bf16x8*>(abase + c * 512);

    float Z0 = 0.f, Z1 = 0.f;
    const int nsteps = jrange >> 5;

    auto k2_step = [&](const bf16x8* Ab, float& Zc) {
        floatx16 a0, a1;
        #pragma unroll
        for (int r = 0; r < 16; ++r) { a0[r] = -m; a1[r] = 0.f; }
        a0 = __builtin_amdgcn_mfma_f32_32x32x16_bf16(Ab[0], Bf[0], a0, 0, 0, 0);
        a1 = __builtin_amdgcn_mfma_f32_32x32x16_bf16(Ab[4], Bf[4], a1, 0, 0, 0);
        a0 = __builtin_amdgcn_mfma_f32_32x32x16_bf16(Ab[1], Bf[1], a0, 0, 0, 0);
        a1 = __builtin_amdgcn_mfma_f32_32x32x16_bf16(Ab[5], Bf[5], a1, 0, 0, 0);
        a0 = __builtin_amdgcn_mfma_f32_32x32x16_bf16(Ab[2], Bf[2], a0, 0, 0, 0);
        a1 = __builtin_amdgcn_mfma_f32_32x32x16_bf16(Ab[6], Bf[6], a1, 0, 0, 0);
        a0 = __builtin_amdgcn_mfma_f32_32x32x16_bf16(Ab[3], Bf[3], a0, 0, 0, 0);
        a1 = __builtin_amdgcn_mfma_f32_32x32x16_bf16(Ab[7], Bf[7], a1, 0, 0, 0);
        float z[16];
        #pragma unroll
        for (int r = 0; r < 16; ++r)
            z[r] = __builtin_amdgcn_exp2f(a0[r] + a1[r]);
        float t0 = (z[0] + z[1]) + (z[2] + z[3]);
        float t1 = (z[4] + z[5]) + (z[6] + z[7]);
        float t2 = (z[8] + z[9]) + (z[10] + z[11]);
        float t3 = (z[12] + z[13]) + (z[14] + z[15]);
        Zc += (t0 + t1) + (t2 + t3);
    };

    for (int s = 0; s < nsteps; s += 2) {
        {   // consume A0 (step s), prefetch s+1 -> A1
            const __bf16* ap = abase + (size_t)(s + 1) * 4096;
            #pragma unroll
            for (int c = 0; c < 8; ++c)
                A1[c] = *reinterpret_cast<const bf16x8*>(ap + c * 512);
            k2_step(A0, Z0);
        }
        {   // consume A1 (step s+1), prefetch s+2 -> A0
            if (s + 2 < nsteps) {
                const __bf16* ap = abase + (size_t)(s + 2) * 4096;
                #pragma unroll
                for (int c = 0; c < 8; ++c)
                    A0[c] = *reinterpret_cast<const bf16x8*>(ap + c * 512);
            }
            k2_step(A1, Z1);
        }
    }

    float Zt = Z0 + Z1;
    Zt += __shfl_xor(Zt, 32);     // lanes l, l+32 hold same i-col
    if (lane < 32)
        part[(size_t)split * B_ROWS + icol] = Zt;
}

// ---- K3: per-row loss; fixed-point global accumulate ----
__global__ __launch_bounds__(128) void k3_rowloss(
        const float* __restrict__ E, const int* __restrict__ labels,
        const unsigned long long* __restrict__ Sfix,
        const unsigned long long* __restrict__ cntfix,
        const float* __restrict__ nrm, const float* __restrict__ part,
        int nsplit, unsigned long long* __restrict__ lossfix,
        unsigned long long* __restrict__ validfix) {
    __shared__ float sS[3][128];
    const int tid = threadIdx.x;
    #pragma unroll
    for (int c = 0; c < 3; ++c)
        sS[c][tid] = (float)(long long)Sfix[c * 128 + tid] * (1.0f / FIX_SCALE);
    __syncthreads();

    const int i = blockIdx.x * 128 + tid;
    const int lab = labels[i];
    const float invt = class_invtemp(lab);

    const float4* er = reinterpret_cast<const float4*>(E + (size_t)i * D_DIM);
    const float4* sr = reinterpret_cast<const float4*>(&sS[lab][0]);
    float dotS = 0.f;
    #pragma unroll
    for (int k4 = 0; k4 < 32; ++k4) {
        float4 v = er[k4];
        float4 s = sr[k4];
        dotS += v.x * s.x + v.y * s.y + v.z * s.z + v.w * s.w;
    }
    const float nr = nrm[i];

    float Zt = 0.f;
    for (int sp = 0; sp < nsplit; ++sp)
        Zt += part[(size_t)sp * B_ROWS + i];

    const float C = (float)(long long)cntfix[lab] - 1.0f;
    // lse_nat = m*ln2 + ln(Zt), m = invt*log2e*nr -> m*ln2 = invt*nr
    const float lse = invt * nr + LN2 * __builtin_amdgcn_logf(Zt);
    const float P_nat = invt * (dotS - nr);
    float loss = -(BASE_TEMP * invt) * (P_nat - C * lse) / (C + 1e-8f);
    int valid = (C > 0.f) ? 1 : 0;
    loss = (C > 0.f) ? loss : 0.f;

    #pragma unroll
    for (int off = 32; off; off >>= 1) {
        loss += __shfl_down(loss, off);
        valid += __shfl_down(valid, off);
    }
    __shared__ float rl[2];
    __shared__ int rv[2];
    if ((tid & 63) == 0) { rl[tid >> 6] = loss; rv[tid >> 6] = valid; }
    __syncthreads();
    if (tid == 0) {
        atomicAdd(lossfix, fix64(rl[0] + rl[1]));
        atomicAdd(validfix, (unsigned long long)(rv[0] + rv[1]));
    }
}

// ---- K4: final scalar ----
__global__ void k4_final(const unsigned long long* __restrict__ lossfix,
                         const unsigned long long* __restrict__ validfix,
                         float* __restrict__ out) {
    if (threadIdx.x == 0) {
        double T = (double)(long long)lossfix[0] * (1.0 / (double)FIX_SCALE);
        float N = (float)(long long)validfix[0];
        out[0] = (N > 0.f) ? (float)(T / (double)fmaxf(N, 1.f)) : 0.f;
    }
}

extern "C" void kernel_launch(void* const* d_in, const int* in_sizes, int n_in,
                              void* d_out, int out_size, void* d_ws, size_t ws_size,
                              hipStream_t stream) {
    const float* E = (const float*)d_in[0];
    const int* labels = (const int*)d_in[1];
    float* out = (float*)d_out;
    char* ws = (char*)d_ws;

    // workspace layout
    const size_t OFF_EBF = 0;                         // 2 MB tiled bf16
    const size_t OFF_ATOM = (size_t)2 << 20;          // 4 KB zeroed accumulators
    const size_t OFF_NRM = OFF_ATOM + 4096;           // 32 KB row norms
    const size_t OFF_PART = OFF_NRM + (size_t)B_ROWS * 4;  // part[split][B]

    int nsplit = 8;
    if (ws_size >= OFF_PART + (size_t)32 * B_ROWS * 4) nsplit = 32;
    else if (ws_size >= OFF_PART + (size_t)16 * B_ROWS * 4) nsplit = 16;
    const int jrange = B_ROWS / nsplit;

    __bf16* Ebf = (__bf16*)(ws + OFF_EBF);
    unsigned long long* Sfix = (unsigned long long*)(ws + OFF_ATOM);      // 3*128*8
    unsigned long long* cntfix = Sfix + 384;                              // 3
    unsigned long long* lossfix = Sfix + 388;
    unsigned long long* validfix = Sfix + 389;
    float* nrm = (float*)(ws + OFF_NRM);
    float* part = (float*)(ws + OFF_PART);

    hipMemsetAsync(ws + OFF_ATOM, 0, 4096, stream);
    k0_prep<<<256, 256, 0, stream>>>(E, labels, Ebf, nrm, Sfix, cntfix);
    k2_stats<<<dim3(64, nsplit), 256, 0, stream>>>(Ebf, labels, nrm, part, nsplit, jrange);
    k3_rowloss<<<64, 128, 0, stream>>>(E, labels, Sfix, cntfix, nrm, part,
                                       nsplit, lossfix, validfix);
    k4_final<<<1, 64, 0, stream>>>(lossfix, validfix, out);
}